// Round 1
// baseline (1807.279 us; speedup 1.0000x reference)
//
#include <hip/hip_runtime.h>
#include <cstddef>

#define L_DIM 2048
#define C_DIM 512
#define CQ_DIM 64
#define B_DIM 8

// ---------------------------------------------------------------------------
// Generic conv1d (K=3, 'same' pad=1): out[b,co,l] = sum_{ci,t} x[b,ci,l+t-1]*W[co,ci,t]
// Tile: 64 co x 64 l per block, ci in chunks of 32. 256 threads, 4co x 4l per thread.
// ---------------------------------------------------------------------------
__global__ __launch_bounds__(256) void conv_k(const float* __restrict__ x,
                                              const float* __restrict__ W,
                                              float* __restrict__ out, int Cout) {
    const int l0  = blockIdx.x * 64;
    const int co0 = blockIdx.y * 64;
    const int b   = blockIdx.z;

    __shared__ float xs[32 * 68];   // [ci][la], la in [0,66), col 0 == global l0-1
    __shared__ float ws[96 * 68];   // [s=ci*3+t][co], co-dim contiguous (float4-aligned rows)

    const int tid = threadIdx.x;
    const int lt = tid & 15;    // l group (4 per thread)
    const int ct = tid >> 4;    // co group (4 per thread)

    float acc[4][4] = {};
    const float* xb = x + (size_t)b * C_DIM * L_DIM;

    for (int ci0 = 0; ci0 < C_DIM; ci0 += 32) {
        __syncthreads();
        // stage x[b, ci0..ci0+32, l0-1 .. l0+65)
        for (int idx = tid; idx < 32 * 66; idx += 256) {
            int ci = idx / 66, la = idx % 66;
            int l = l0 - 1 + la;
            float vx = 0.f;
            if (l >= 0 && l < L_DIM) vx = xb[(ci0 + ci) * L_DIM + l];
            xs[ci * 68 + la] = vx;
        }
        // stage W[co0..co0+64, ci0..ci0+32, 0..3): contiguous 96-elem runs per co
        for (int idx = tid; idx < 96 * 64; idx += 256) {
            int co = idx / 96, s = idx % 96;
            ws[s * 68 + co] = W[(size_t)(co0 + co) * (C_DIM * 3) + ci0 * 3 + s];
        }
        __syncthreads();

        for (int ci = 0; ci < 32; ci++) {
            float xa[6];
            const float4 xq = *(const float4*)&xs[ci * 68 + lt * 4];
            xa[0] = xq.x; xa[1] = xq.y; xa[2] = xq.z; xa[3] = xq.w;
            xa[4] = xs[ci * 68 + lt * 4 + 4];
            xa[5] = xs[ci * 68 + lt * 4 + 5];
#pragma unroll
            for (int t = 0; t < 3; t++) {
                const float4 w4 = *(const float4*)&ws[(ci * 3 + t) * 68 + ct * 4];
                const float wa[4] = {w4.x, w4.y, w4.z, w4.w};
#pragma unroll
                for (int a = 0; a < 4; a++)
#pragma unroll
                    for (int u = 0; u < 4; u++)
                        acc[a][u] += wa[a] * xa[u + t];
            }
        }
    }

    float* ob = out + ((size_t)b * Cout + co0) * L_DIM;
#pragma unroll
    for (int a = 0; a < 4; a++) {
        float4 r;
        r.x = acc[a][0]; r.y = acc[a][1]; r.z = acc[a][2]; r.w = acc[a][3];
        *(float4*)&ob[(ct * 4 + a) * L_DIM + l0 + lt * 4] = r;
    }
}

// ---------------------------------------------------------------------------
// Softmax stats: for each (b, j) compute m_j = max_i s[i,j], d_j = sum_i exp(s-m).
// s[i,j] = sum_c q[b,c,i] * k[b,c,j]. One block per (j-tile of 64, b). 256 threads.
// ---------------------------------------------------------------------------
__global__ __launch_bounds__(256) void stats_k(const float* __restrict__ q,
                                               const float* __restrict__ k,
                                               float* __restrict__ mG,
                                               float* __restrict__ dG) {
    const int j0 = blockIdx.x * 64;
    const int b  = blockIdx.y;

    __shared__ float kk[64 * 64];   // [c][j]
    __shared__ float qq[64 * 64];   // [c][i]
    __shared__ float ss[64 * 64];   // [i][j]
    __shared__ float red[4 * 64];
    __shared__ float m_s[64], d_s[64];

    const int tid = threadIdx.x;
    const float* qb = q + (size_t)b * CQ_DIM * L_DIM;
    const float* kb = k + (size_t)b * CQ_DIM * L_DIM;

    for (int idx = tid; idx < 4096; idx += 256) {
        int c = idx >> 6, j = idx & 63;
        kk[idx] = kb[c * L_DIM + j0 + j];
    }
    if (tid < 64) { m_s[tid] = -1e30f; d_s[tid] = 0.f; }

    const int it = tid >> 4, jt = tid & 15;   // score tiling: 4i x 4j per thread
    const int jcol = tid & 63, part = tid >> 6;

    for (int i0 = 0; i0 < L_DIM; i0 += 64) {
        __syncthreads();
        for (int idx = tid; idx < 4096; idx += 256) {
            int c = idx >> 6, i = idx & 63;
            qq[idx] = qb[c * L_DIM + i0 + i];
        }
        __syncthreads();

        float sacc[4][4] = {};
        for (int c = 0; c < 64; c++) {
            const float4 q4 = *(const float4*)&qq[c * 64 + it * 4];
            const float4 k4 = *(const float4*)&kk[c * 64 + jt * 4];
            const float qa[4] = {q4.x, q4.y, q4.z, q4.w};
            const float ka[4] = {k4.x, k4.y, k4.z, k4.w};
#pragma unroll
            for (int ui = 0; ui < 4; ui++)
#pragma unroll
                for (int uj = 0; uj < 4; uj++)
                    sacc[ui][uj] += qa[ui] * ka[uj];
        }
#pragma unroll
        for (int ui = 0; ui < 4; ui++) {
            float4 r;
            r.x = sacc[ui][0]; r.y = sacc[ui][1]; r.z = sacc[ui][2]; r.w = sacc[ui][3];
            *(float4*)&ss[(it * 4 + ui) * 64 + jt * 4] = r;
        }
        __syncthreads();

        // column max over this i-block (4 partial threads per column)
        float lm = -1e30f;
        for (int r = 0; r < 16; r++) lm = fmaxf(lm, ss[(part * 16 + r) * 64 + jcol]);
        red[part * 64 + jcol] = lm;
        __syncthreads();
        if (part == 0) {
            float mb = fmaxf(fmaxf(red[jcol], red[64 + jcol]),
                             fmaxf(red[128 + jcol], red[192 + jcol]));
            float mo = m_s[jcol];
            float mn = fmaxf(mo, mb);
            d_s[jcol] *= __expf(mo - mn);
            m_s[jcol] = mn;
        }
        __syncthreads();
        float mj = m_s[jcol];
        float lsum = 0.f;
        for (int r = 0; r < 16; r++) lsum += __expf(ss[(part * 16 + r) * 64 + jcol] - mj);
        red[part * 64 + jcol] = lsum;
        __syncthreads();
        if (part == 0)
            d_s[jcol] += red[jcol] + red[64 + jcol] + red[128 + jcol] + red[192 + jcol];
    }
    __syncthreads();
    if (tid < 64) {
        mG[b * L_DIM + j0 + tid] = m_s[tid];
        dG[b * L_DIM + j0 + tid] = d_s[tid];
    }
}

// ---------------------------------------------------------------------------
// PV: out[b, co, j] = gamma * sum_i v[b,co,i] * exp(s[i,j]-m_j)/d_j
// Grid (32 j-tiles, 4 co-splits of 128, 8 b). 512 threads.
// ---------------------------------------------------------------------------
__global__ __launch_bounds__(512) void pv_k(const float* __restrict__ q,
                                            const float* __restrict__ k,
                                            const float* __restrict__ v,
                                            const float* __restrict__ mG,
                                            const float* __restrict__ dG,
                                            const float* __restrict__ gamma,
                                            float* __restrict__ out) {
    const int j0  = blockIdx.x * 64;
    const int co0 = blockIdx.y * 128;
    const int b   = blockIdx.z;

    __shared__ float kk[64 * 64];   // [c][j]
    __shared__ float qq[64 * 64];   // [c][i]
    __shared__ float ss[64 * 64];   // p[i][j]
    __shared__ float vv[128 * 66];  // [cc][ii]
    __shared__ float mj_s[64], id_s[64];

    const int tid = threadIdx.x;
    const float* qb = q + (size_t)b * CQ_DIM * L_DIM;
    const float* kb = k + (size_t)b * CQ_DIM * L_DIM;
    const float* vb = v + (size_t)b * C_DIM * L_DIM;

    for (int idx = tid; idx < 4096; idx += 512) {
        int c = idx >> 6, j = idx & 63;
        kk[idx] = kb[c * L_DIM + j0 + j];
    }
    if (tid < 64) {
        mj_s[tid] = mG[b * L_DIM + j0 + tid];
        id_s[tid] = 1.0f / dG[b * L_DIM + j0 + tid];
    }

    const int it  = tid >> 4;   // 0..31: i base it*2 (scores phase)
    const int jt4 = tid & 15;   // j base jt4*4      (scores phase)
    const int ct  = tid >> 3;   // 0..63: co base ct*2 (PV phase)
    const int jt8 = tid & 7;    // j base jt8*8       (PV phase)

    float acc[2][8] = {};

    for (int i0 = 0; i0 < L_DIM; i0 += 64) {
        __syncthreads();
        for (int idx = tid; idx < 4096; idx += 512) {
            int c = idx >> 6, i = idx & 63;
            qq[idx] = qb[c * L_DIM + i0 + i];
        }
        for (int idx = tid; idx < 8192; idx += 512) {
            int cc = idx >> 6, ii = idx & 63;
            vv[cc * 66 + ii] = vb[(size_t)(co0 + cc) * L_DIM + i0 + ii];
        }
        __syncthreads();

        // scores (2i x 4j per thread) -> p = exp(s - m_j) / d_j
        float s0[4] = {}, s1[4] = {};
        for (int c = 0; c < 64; c++) {
            const float2 q2 = *(const float2*)&qq[c * 64 + it * 2];
            const float4 k4 = *(const float4*)&kk[c * 64 + jt4 * 4];
            const float ka[4] = {k4.x, k4.y, k4.z, k4.w};
#pragma unroll
            for (int u = 0; u < 4; u++) {
                s0[u] += q2.x * ka[u];
                s1[u] += q2.y * ka[u];
            }
        }
        float4 p0, p1;
        {
            float pa[4], pb[4];
#pragma unroll
            for (int u = 0; u < 4; u++) {
                const float m  = mj_s[jt4 * 4 + u];
                const float iv = id_s[jt4 * 4 + u];
                pa[u] = __expf(s0[u] - m) * iv;
                pb[u] = __expf(s1[u] - m) * iv;
            }
            p0.x = pa[0]; p0.y = pa[1]; p0.z = pa[2]; p0.w = pa[3];
            p1.x = pb[0]; p1.y = pb[1]; p1.z = pb[2]; p1.w = pb[3];
        }
        *(float4*)&ss[(it * 2) * 64 + jt4 * 4] = p0;
        *(float4*)&ss[(it * 2 + 1) * 64 + jt4 * 4] = p1;
        __syncthreads();

        // PV accumulate: 2co x 8j per thread
        for (int ii = 0; ii < 64; ii++) {
            const float v0 = vv[(ct * 2) * 66 + ii];
            const float v1 = vv[(ct * 2 + 1) * 66 + ii];
            const float4 pa = *(const float4*)&ss[ii * 64 + jt8 * 8];
            const float4 pb = *(const float4*)&ss[ii * 64 + jt8 * 8 + 4];
            acc[0][0] += v0 * pa.x; acc[0][1] += v0 * pa.y;
            acc[0][2] += v0 * pa.z; acc[0][3] += v0 * pa.w;
            acc[0][4] += v0 * pb.x; acc[0][5] += v0 * pb.y;
            acc[0][6] += v0 * pb.z; acc[0][7] += v0 * pb.w;
            acc[1][0] += v1 * pa.x; acc[1][1] += v1 * pa.y;
            acc[1][2] += v1 * pa.z; acc[1][3] += v1 * pa.w;
            acc[1][4] += v1 * pb.x; acc[1][5] += v1 * pb.y;
            acc[1][6] += v1 * pb.z; acc[1][7] += v1 * pb.w;
        }
    }

    const float g = gamma[0];
#pragma unroll
    for (int a = 0; a < 2; a++) {
        const int row = co0 + ct * 2 + a;
        float* ob = out + ((size_t)b * C_DIM + row) * L_DIM + j0 + jt8 * 8;
        float4 r0, r1;
        r0.x = acc[a][0] * g; r0.y = acc[a][1] * g; r0.z = acc[a][2] * g; r0.w = acc[a][3] * g;
        r1.x = acc[a][4] * g; r1.y = acc[a][5] * g; r1.z = acc[a][6] * g; r1.w = acc[a][7] * g;
        *(float4*)&ob[0] = r0;
        *(float4*)&ob[4] = r1;
    }
}

// ---------------------------------------------------------------------------
extern "C" void kernel_launch(void* const* d_in, const int* in_sizes, int n_in,
                              void* d_out, int out_size, void* d_ws, size_t ws_size,
                              hipStream_t stream) {
    const float* x     = (const float*)d_in[0];
    const float* Wq    = (const float*)d_in[1];
    const float* Wk    = (const float*)d_in[2];
    const float* Wv    = (const float*)d_in[3];
    const float* gamma = (const float*)d_in[4];
    float* out = (float*)d_out;

    float* ws_f = (float*)d_ws;
    float* q_ws = ws_f;                      // 8*64*2048   = 1,048,576 floats
    float* k_ws = q_ws + 1048576;
    float* v_ws = k_ws + 1048576;            // 8*512*2048  = 8,388,608 floats
    float* mG   = v_ws + 8388608;            // 8*2048      = 16,384 floats
    float* dG   = mG + 16384;
    // total ~40.2 MB of workspace

    conv_k<<<dim3(32, 1, 8), 256, 0, stream>>>(x, Wq, q_ws, CQ_DIM);
    conv_k<<<dim3(32, 1, 8), 256, 0, stream>>>(x, Wk, k_ws, CQ_DIM);
    conv_k<<<dim3(32, 8, 8), 256, 0, stream>>>(x, Wv, v_ws, C_DIM);
    stats_k<<<dim3(32, 8), 256, 0, stream>>>(q_ws, k_ws, mG, dG);
    pv_k<<<dim3(32, 4, 8), 512, 0, stream>>>(q_ws, k_ws, v_ws, mG, dG, gamma, out);
}

// Round 3
// 918.621 us; speedup vs baseline: 1.9674x; 1.9674x over previous
//
#include <hip/hip_runtime.h>
#include <cstddef>

#define L_DIM 2048
#define C_DIM 512
#define CQ_DIM 64
#define B_DIM 8

typedef _Float16 f16x8 __attribute__((ext_vector_type(8)));
typedef float f32x4 __attribute__((ext_vector_type(4)));

__device__ __forceinline__ unsigned short f2h(float f) {
    union { _Float16 h; unsigned short u; } v;
    v.h = (_Float16)f;   // v_cvt_f16_f32, round-to-nearest-even
    return v.u;
}

// ---------------------------------------------------------------------------
// conv1d for q/k (Cout=64): fp32 math, fp16 TRANSPOSED output qT[b][l][c]
// Tile 64co x 64l, ci chunks of 32. 256 threads, 4co x 4l per thread.
// ---------------------------------------------------------------------------
__global__ __launch_bounds__(256) void conv_qk(const float* __restrict__ x,
                                               const float* __restrict__ W,
                                               unsigned short* __restrict__ outT) {
    const int l0 = blockIdx.x * 64;
    const int b  = blockIdx.z;

    __shared__ float xs[32 * 68];
    __shared__ float ws[96 * 68];

    const int tid = threadIdx.x;
    const int lt = tid & 15;
    const int ct = tid >> 4;

    float acc[4][4] = {};
    const float* xb = x + (size_t)b * C_DIM * L_DIM;

    for (int ci0 = 0; ci0 < C_DIM; ci0 += 32) {
        __syncthreads();
        for (int idx = tid; idx < 32 * 66; idx += 256) {
            int ci = idx / 66, la = idx % 66;
            int l = l0 - 1 + la;
            float vx = 0.f;
            if (l >= 0 && l < L_DIM) vx = xb[(ci0 + ci) * L_DIM + l];
            xs[ci * 68 + la] = vx;
        }
        for (int idx = tid; idx < 96 * 64; idx += 256) {
            int co = idx / 96, s = idx % 96;
            ws[s * 68 + co] = W[(size_t)co * (C_DIM * 3) + ci0 * 3 + s];
        }
        __syncthreads();

        for (int ci = 0; ci < 32; ci++) {
            float xa[6];
            const float4 xq = *(const float4*)&xs[ci * 68 + lt * 4];
            xa[0] = xq.x; xa[1] = xq.y; xa[2] = xq.z; xa[3] = xq.w;
            xa[4] = xs[ci * 68 + lt * 4 + 4];
            xa[5] = xs[ci * 68 + lt * 4 + 5];
#pragma unroll
            for (int t = 0; t < 3; t++) {
                const float4 w4 = *(const float4*)&ws[(ci * 3 + t) * 68 + ct * 4];
                const float wa[4] = {w4.x, w4.y, w4.z, w4.w};
#pragma unroll
                for (int a = 0; a < 4; a++)
#pragma unroll
                    for (int u = 0; u < 4; u++)
                        acc[a][u] += wa[a] * xa[u + t];
            }
        }
    }

    unsigned short* ob = outT + (size_t)b * L_DIM * CQ_DIM;
#pragma unroll
    for (int u = 0; u < 4; u++) {
        const int l = l0 + lt * 4 + u;
        ushort4 r;
        r.x = f2h(acc[0][u]); r.y = f2h(acc[1][u]);
        r.z = f2h(acc[2][u]); r.w = f2h(acc[3][u]);
        *(ushort4*)&ob[(size_t)l * CQ_DIM + ct * 4] = r;
    }
}

// ---------------------------------------------------------------------------
// conv1d for v (Cout=512): fp32 math, fp16 natural output v[b][co][l]
// ---------------------------------------------------------------------------
__global__ __launch_bounds__(256) void conv_v(const float* __restrict__ x,
                                              const float* __restrict__ W,
                                              unsigned short* __restrict__ out) {
    const int l0  = blockIdx.x * 64;
    const int co0 = blockIdx.y * 64;
    const int b   = blockIdx.z;

    __shared__ float xs[32 * 68];
    __shared__ float ws[96 * 68];

    const int tid = threadIdx.x;
    const int lt = tid & 15;
    const int ct = tid >> 4;

    float acc[4][4] = {};
    const float* xb = x + (size_t)b * C_DIM * L_DIM;

    for (int ci0 = 0; ci0 < C_DIM; ci0 += 32) {
        __syncthreads();
        for (int idx = tid; idx < 32 * 66; idx += 256) {
            int ci = idx / 66, la = idx % 66;
            int l = l0 - 1 + la;
            float vx = 0.f;
            if (l >= 0 && l < L_DIM) vx = xb[(ci0 + ci) * L_DIM + l];
            xs[ci * 68 + la] = vx;
        }
        for (int idx = tid; idx < 96 * 64; idx += 256) {
            int co = idx / 96, s = idx % 96;
            ws[s * 68 + co] = W[(size_t)(co0 + co) * (C_DIM * 3) + ci0 * 3 + s];
        }
        __syncthreads();

        for (int ci = 0; ci < 32; ci++) {
            float xa[6];
            const float4 xq = *(const float4*)&xs[ci * 68 + lt * 4];
            xa[0] = xq.x; xa[1] = xq.y; xa[2] = xq.z; xa[3] = xq.w;
            xa[4] = xs[ci * 68 + lt * 4 + 4];
            xa[5] = xs[ci * 68 + lt * 4 + 5];
#pragma unroll
            for (int t = 0; t < 3; t++) {
                const float4 w4 = *(const float4*)&ws[(ci * 3 + t) * 68 + ct * 4];
                const float wa[4] = {w4.x, w4.y, w4.z, w4.w};
#pragma unroll
                for (int a = 0; a < 4; a++)
#pragma unroll
                    for (int u = 0; u < 4; u++)
                        acc[a][u] += wa[a] * xa[u + t];
            }
        }
    }

    unsigned short* ob = out + ((size_t)b * C_DIM + co0) * L_DIM;
#pragma unroll
    for (int a = 0; a < 4; a++) {
        ushort4 r;
        r.x = f2h(acc[a][0]); r.y = f2h(acc[a][1]);
        r.z = f2h(acc[a][2]); r.w = f2h(acc[a][3]);
        *(ushort4*)&ob[(ct * 4 + a) * L_DIM + l0 + lt * 4] = r;
    }
}

// ---------------------------------------------------------------------------
// Softmax stats via MFMA (fp16): m_j = max_i s[i,j], d_j = sum_i exp(s-m_j).
// qT/kT are fp16 [b][l][64c]. One block per (64-j tile, b). 256 threads (4 waves).
// ---------------------------------------------------------------------------
__global__ __launch_bounds__(256) void stats_k(const unsigned short* __restrict__ qT,
                                               const unsigned short* __restrict__ kT,
                                               float* __restrict__ mG,
                                               float* __restrict__ dG) {
    const int j0 = blockIdx.x * 64;
    const int b  = blockIdx.y;

    __shared__ unsigned short kTs[64 * 72];
    __shared__ unsigned short qTs[64 * 72];
    __shared__ float ss[64 * 68];
    __shared__ float red[4 * 64];
    __shared__ float m_s[64], d_s[64];

    const int tid = threadIdx.x;
    const int lane = tid & 63, w = tid >> 6;
    const int ln15 = lane & 15, quad = lane >> 4;
    const int jcol = tid & 63, part = tid >> 6;

    const unsigned short* qb = qT + (size_t)b * L_DIM * CQ_DIM;
    const unsigned short* kb = kT + (size_t)b * L_DIM * CQ_DIM;

    for (int idx = tid; idx < 64 * 8; idx += 256) {
        int r = idx >> 3, c8 = idx & 7;
        *(float4*)&kTs[r * 72 + c8 * 8] = *(const float4*)&kb[(size_t)(j0 + r) * CQ_DIM + c8 * 8];
    }
    if (tid < 64) { m_s[tid] = -1e30f; d_s[tid] = 0.f; }

    for (int i0 = 0; i0 < L_DIM; i0 += 64) {
        __syncthreads();
        for (int idx = tid; idx < 64 * 8; idx += 256) {
            int r = idx >> 3, c8 = idx & 7;
            *(float4*)&qTs[r * 72 + c8 * 8] = *(const float4*)&qb[(size_t)(i0 + r) * CQ_DIM + c8 * 8];
        }
        __syncthreads();

        // wave w covers j-subtile w*16; i-tiles 0..3
        f32x4 acc[4] = {};
#pragma unroll
        for (int cc = 0; cc < 2; cc++) {
            const f16x8 bfr = *(const f16x8*)&kTs[(w * 16 + ln15) * 72 + cc * 32 + quad * 8];
#pragma unroll
            for (int it = 0; it < 4; it++) {
                const f16x8 afr = *(const f16x8*)&qTs[(it * 16 + ln15) * 72 + cc * 32 + quad * 8];
                acc[it] = __builtin_amdgcn_mfma_f32_16x16x32_f16(afr, bfr, acc[it], 0, 0, 0);
            }
        }
#pragma unroll
        for (int it = 0; it < 4; it++)
#pragma unroll
            for (int r = 0; r < 4; r++)
                ss[(it * 16 + quad * 4 + r) * 68 + w * 16 + ln15] = acc[it][r];
        __syncthreads();

        float lm = -1e30f;
        for (int r = 0; r < 16; r++) lm = fmaxf(lm, ss[(part * 16 + r) * 68 + jcol]);
        red[part * 64 + jcol] = lm;
        __syncthreads();
        if (part == 0) {
            float mb = fmaxf(fmaxf(red[jcol], red[64 + jcol]),
                             fmaxf(red[128 + jcol], red[192 + jcol]));
            float mo = m_s[jcol];
            float mn = fmaxf(mo, mb);
            d_s[jcol] *= __expf(mo - mn);
            m_s[jcol] = mn;
        }
        __syncthreads();
        const float mj = m_s[jcol];
        float lsum = 0.f;
        for (int r = 0; r < 16; r++) lsum += __expf(ss[(part * 16 + r) * 68 + jcol] - mj);
        red[part * 64 + jcol] = lsum;
        __syncthreads();
        if (part == 0)
            d_s[jcol] += red[jcol] + red[64 + jcol] + red[128 + jcol] + red[192 + jcol];
    }
    __syncthreads();
    if (tid < 64) {
        mG[b * L_DIM + j0 + tid] = m_s[tid];
        dG[b * L_DIM + j0 + tid] = d_s[tid];
    }
}

// ---------------------------------------------------------------------------
// PV via MFMA (fp16): out[b,co,j] = gamma * sum_i v[b,co,i] * exp(s[i,j]-m_j)/d_j
// Block: 256 threads (4 waves), out tile 128co x 128j. Grid (16 j, 4 co, 8 b).
// ---------------------------------------------------------------------------
__global__ __launch_bounds__(256) void pv_k(const unsigned short* __restrict__ qT,
                                            const unsigned short* __restrict__ kT,
                                            const unsigned short* __restrict__ vB,
                                            const float* __restrict__ mG,
                                            const float* __restrict__ dG,
                                            const float* __restrict__ gamma,
                                            float* __restrict__ out) {
    const int j0  = blockIdx.x * 128;
    const int co0 = blockIdx.y * 128;
    const int b   = blockIdx.z;

    __shared__ unsigned short kTs[128 * 72];  // [j][c]
    __shared__ unsigned short qTs[64 * 72];   // [i][c]
    __shared__ unsigned short vvs[128 * 72];  // [co][i]
    __shared__ unsigned short pps[128 * 72];  // [j][i]
    __shared__ float mj_s[128], id_s[128];

    const int tid = threadIdx.x;
    const int lane = tid & 63, w = tid >> 6;
    const int ln15 = lane & 15, quad = lane >> 4;

    const unsigned short* qb = qT + (size_t)b * L_DIM * CQ_DIM;
    const unsigned short* kb = kT + (size_t)b * L_DIM * CQ_DIM;
    const unsigned short* vb = vB + (size_t)b * C_DIM * L_DIM;

    for (int idx = tid; idx < 128 * 8; idx += 256) {
        int r = idx >> 3, c8 = idx & 7;
        *(float4*)&kTs[r * 72 + c8 * 8] = *(const float4*)&kb[(size_t)(j0 + r) * CQ_DIM + c8 * 8];
    }
    if (tid < 128) {
        mj_s[tid] = mG[b * L_DIM + j0 + tid];
        id_s[tid] = 1.0f / dG[b * L_DIM + j0 + tid];
    }

    const int wco = (w >> 1) * 64;  // PV phase: wave's co range within 128
    const int wj  = (w & 1) * 64;   // PV phase: wave's j range within 128
    const int sj  = w * 32;         // scores phase: wave's j range within 128

    f32x4 oacc[4][4] = {};

    for (int i0 = 0; i0 < L_DIM; i0 += 64) {
        __syncthreads();
        for (int idx = tid; idx < 64 * 8; idx += 256) {
            int r = idx >> 3, c8 = idx & 7;
            *(float4*)&qTs[r * 72 + c8 * 8] = *(const float4*)&qb[(size_t)(i0 + r) * CQ_DIM + c8 * 8];
        }
        for (int idx = tid; idx < 128 * 8; idx += 256) {
            int r = idx >> 3, c8 = idx & 7;
            *(float4*)&vvs[r * 72 + c8 * 8] = *(const float4*)&vb[(size_t)(co0 + r) * L_DIM + i0 + c8 * 8];
        }
        __syncthreads();

        // scores: wave computes S[64i x 32j] at j = sj..sj+32
        f32x4 sacc[4][2] = {};
#pragma unroll
        for (int cc = 0; cc < 2; cc++) {
            f16x8 bfr0 = *(const f16x8*)&kTs[(sj + ln15) * 72 + cc * 32 + quad * 8];
            f16x8 bfr1 = *(const f16x8*)&kTs[(sj + 16 + ln15) * 72 + cc * 32 + quad * 8];
#pragma unroll
            for (int it = 0; it < 4; it++) {
                const f16x8 afr = *(const f16x8*)&qTs[(it * 16 + ln15) * 72 + cc * 32 + quad * 8];
                sacc[it][0] = __builtin_amdgcn_mfma_f32_16x16x32_f16(afr, bfr0, sacc[it][0], 0, 0, 0);
                sacc[it][1] = __builtin_amdgcn_mfma_f32_16x16x32_f16(afr, bfr1, sacc[it][1], 0, 0, 0);
            }
        }
        // p = exp(s - m_j) / d_j -> fp16 -> pps[j][i]
#pragma unroll
        for (int jt = 0; jt < 2; jt++) {
            const int j = sj + jt * 16 + ln15;
            const float m = mj_s[j], idv = id_s[j];
#pragma unroll
            for (int it = 0; it < 4; it++) {
                ushort4 r4;
                r4.x = f2h(__expf(sacc[it][jt][0] - m) * idv);
                r4.y = f2h(__expf(sacc[it][jt][1] - m) * idv);
                r4.z = f2h(__expf(sacc[it][jt][2] - m) * idv);
                r4.w = f2h(__expf(sacc[it][jt][3] - m) * idv);
                *(ushort4*)&pps[j * 72 + it * 16 + quad * 4] = r4;
            }
        }
        __syncthreads();

        // PV: oacc[64co x 64j] += V[64co x 64i] * P[64i x 64j]
#pragma unroll
        for (int cc = 0; cc < 2; cc++) {
            f16x8 afr[4], bfr[4];
#pragma unroll
            for (int t = 0; t < 4; t++)
                afr[t] = *(const f16x8*)&vvs[(wco + t * 16 + ln15) * 72 + cc * 32 + quad * 8];
#pragma unroll
            for (int t = 0; t < 4; t++)
                bfr[t] = *(const f16x8*)&pps[(wj + t * 16 + ln15) * 72 + cc * 32 + quad * 8];
#pragma unroll
            for (int a = 0; a < 4; a++)
#pragma unroll
                for (int bb = 0; bb < 4; bb++)
                    oacc[a][bb] = __builtin_amdgcn_mfma_f32_16x16x32_f16(afr[a], bfr[bb], oacc[a][bb], 0, 0, 0);
        }
    }

    const float g = gamma[0];
#pragma unroll
    for (int a = 0; a < 4; a++)
#pragma unroll
        for (int r = 0; r < 4; r++) {
            const int co = co0 + wco + a * 16 + quad * 4 + r;
            float* ob = out + ((size_t)b * C_DIM + co) * L_DIM + j0 + wj;
#pragma unroll
            for (int bb = 0; bb < 4; bb++)
                ob[bb * 16 + ln15] = oacc[a][bb][r] * g;
        }
}

// ---------------------------------------------------------------------------
extern "C" void kernel_launch(void* const* d_in, const int* in_sizes, int n_in,
                              void* d_out, int out_size, void* d_ws, size_t ws_size,
                              hipStream_t stream) {
    const float* x     = (const float*)d_in[0];
    const float* Wq    = (const float*)d_in[1];
    const float* Wk    = (const float*)d_in[2];
    const float* Wv    = (const float*)d_in[3];
    const float* gamma = (const float*)d_in[4];
    float* out = (float*)d_out;

    unsigned short* ws_h = (unsigned short*)d_ws;
    unsigned short* qT = ws_h;                        // 8*2048*64  = 1,048,576
    unsigned short* kT = qT + 1048576;
    unsigned short* vB = kT + 1048576;                // 8*512*2048 = 8,388,608
    float* mG = (float*)(vB + 8388608);               // 16,384 floats
    float* dG = mG + 16384;                           // total ~21 MB

    conv_qk<<<dim3(32, 1, 8), 256, 0, stream>>>(x, Wq, qT);
    conv_qk<<<dim3(32, 1, 8), 256, 0, stream>>>(x, Wk, kT);
    conv_v <<<dim3(32, 8, 8), 256, 0, stream>>>(x, Wv, vB);
    stats_k<<<dim3(32, 8), 256, 0, stream>>>(qT, kT, mG, dG);
    pv_k   <<<dim3(16, 4, 8), 256, 0, stream>>>(qT, kT, vB, mG, dG, gamma, out);
}

// Round 4
// 312.931 us; speedup vs baseline: 5.7753x; 2.9355x over previous
//
#include <hip/hip_runtime.h>
#include <cstddef>

#define L_DIM 2048
#define C_DIM 512
#define CQ_DIM 64
#define B_DIM 8

typedef _Float16 f16x8 __attribute__((ext_vector_type(8)));
typedef float f32x4 __attribute__((ext_vector_type(4)));

__device__ __forceinline__ unsigned short f2h(float f) {
    union { _Float16 h; unsigned short u; } v;
    v.h = (_Float16)f;
    return v.u;
}

// ---------------------------------------------------------------------------
// prep_w: Wq/Wk/Wv (fp32 [co][ci][3]) -> Wh fp16 [t][640co][512ci]
// co 0..63 = q, 64..127 = k, 128..639 = v
// ---------------------------------------------------------------------------
__global__ __launch_bounds__(256) void prep_w(const float* __restrict__ Wq,
                                              const float* __restrict__ Wk,
                                              const float* __restrict__ Wv,
                                              unsigned short* __restrict__ Wh) {
    const int idx = blockIdx.x * 256 + threadIdx.x;   // < 3*640*512
    const int ci = idx & 511;
    const int co = (idx >> 9) % 640;
    const int t  = idx / (640 * 512);
    float w;
    if (co < 64)       w = Wq[(size_t)co * 1536 + ci * 3 + t];
    else if (co < 128) w = Wk[(size_t)(co - 64) * 1536 + ci * 3 + t];
    else               w = Wv[(size_t)(co - 128) * 1536 + ci * 3 + t];
    Wh[idx] = f2h(w);
}

// ---------------------------------------------------------------------------
// prep_x: x fp32 [b][ci][l] -> xT fp16 [b][l][512ci]. 64ci x 64l tile per block.
// ---------------------------------------------------------------------------
__global__ __launch_bounds__(256) void prep_x(const float* __restrict__ x,
                                              unsigned short* __restrict__ xT) {
    const int l0  = blockIdx.x * 64;
    const int ci0 = blockIdx.y * 64;
    const int b   = blockIdx.z;

    __shared__ float xs[64][68];
    const int tid = threadIdx.x;
    const float* xb = x + ((size_t)b * C_DIM + ci0) * L_DIM;

    for (int idx = tid; idx < 64 * 16; idx += 256) {
        int ci = idx >> 4, lq = idx & 15;
        *(float4*)&xs[ci][lq * 4] = *(const float4*)&xb[(size_t)ci * L_DIM + l0 + lq * 4];
    }
    __syncthreads();

    unsigned short* ob = xT + ((size_t)b * L_DIM + l0) * C_DIM + ci0;
    for (int idx = tid; idx < 64 * 8; idx += 256) {
        int l = idx >> 3, c8 = idx & 7;
        ushort4 r0, r1;
        r0.x = f2h(xs[c8 * 8 + 0][l]); r0.y = f2h(xs[c8 * 8 + 1][l]);
        r0.z = f2h(xs[c8 * 8 + 2][l]); r0.w = f2h(xs[c8 * 8 + 3][l]);
        r1.x = f2h(xs[c8 * 8 + 4][l]); r1.y = f2h(xs[c8 * 8 + 5][l]);
        r1.z = f2h(xs[c8 * 8 + 6][l]); r1.w = f2h(xs[c8 * 8 + 7][l]);
        *(ushort4*)&ob[(size_t)l * C_DIM + c8 * 8] = r0;
        *(ushort4*)&ob[(size_t)l * C_DIM + c8 * 8 + 4] = r1;
    }
}

// ---------------------------------------------------------------------------
// conv_all: out[co,l] = sum_t sum_ci Wh[t][co][ci] * x[ci][l+t-1] via MFMA.
// Block tile 64co x 128l, 4 waves each 32co x 64l. ci chunks of 32.
// co0 == 0 -> qT (transposed), co0 == 64 -> kT, else vB natural [co][l].
// ---------------------------------------------------------------------------
__global__ __launch_bounds__(256) void conv_all(const unsigned short* __restrict__ Wh,
                                                const unsigned short* __restrict__ xT,
                                                unsigned short* __restrict__ qT,
                                                unsigned short* __restrict__ kT,
                                                unsigned short* __restrict__ vB) {
    const int l0  = blockIdx.x * 128;
    const int co0 = blockIdx.y * 64;
    const int b   = blockIdx.z;

    __shared__ unsigned short As[3][64][40];   // [t][co][ci32] rows padded to 40
    __shared__ unsigned short Bs[130][40];     // [la][ci32], la 0 == l0-1

    const int tid  = threadIdx.x;
    const int lane = tid & 63, w = tid >> 6;
    const int ln15 = lane & 15, quad = lane >> 4;

    const int co_w = (w & 1) * 32;   // wave's co offset within 64
    const int l_w  = (w >> 1) * 64;  // wave's l offset within 128

    const unsigned short* xb = xT + (size_t)b * L_DIM * C_DIM;

    f32x4 acc[2][4] = {};   // [ct co-tile][lt l-tile]

    for (int ci0 = 0; ci0 < C_DIM; ci0 += 32) {
        __syncthreads();
        // stage A: 3t x 64co x 32ci (float4 = 8 shorts)
        for (int idx = tid; idx < 768; idx += 256) {
            int t = idx >> 8, co = (idx >> 2) & 63, c8 = idx & 3;
            *(float4*)&As[t][co][c8 * 8] =
                *(const float4*)&Wh[(((size_t)t * 640) + co0 + co) * C_DIM + ci0 + c8 * 8];
        }
        // stage B: 130 rows (l0-1 .. l0+128) x 32ci
        for (int idx = tid; idx < 520; idx += 256) {
            int la = idx >> 2, c8 = idx & 3;
            int l = l0 - 1 + la;
            float4 vx = {0.f, 0.f, 0.f, 0.f};
            if (l >= 0 && l < L_DIM)
                vx = *(const float4*)&xb[(size_t)l * C_DIM + ci0 + c8 * 8];
            *(float4*)&Bs[la][c8 * 8] = vx;
        }
        __syncthreads();

#pragma unroll
        for (int t = 0; t < 3; t++) {
            f16x8 a[2], bfr[4];
#pragma unroll
            for (int ct = 0; ct < 2; ct++)
                a[ct] = *(const f16x8*)&As[t][co_w + ct * 16 + ln15][quad * 8];
#pragma unroll
            for (int lt = 0; lt < 4; lt++)
                bfr[lt] = *(const f16x8*)&Bs[l_w + lt * 16 + ln15 + t][quad * 8];
#pragma unroll
            for (int ct = 0; ct < 2; ct++)
#pragma unroll
                for (int lt = 0; lt < 4; lt++)
                    acc[ct][lt] = __builtin_amdgcn_mfma_f32_16x16x32_f16(a[ct], bfr[lt], acc[ct][lt], 0, 0, 0);
        }
    }

    if (co0 < 128) {
        // q or k: write transposed [l][64co]
        unsigned short* dst = (co0 == 0 ? qT : kT) + (size_t)b * L_DIM * CQ_DIM;
#pragma unroll
        for (int ct = 0; ct < 2; ct++)
#pragma unroll
            for (int lt = 0; lt < 4; lt++) {
                const int l = l0 + l_w + lt * 16 + ln15;
                ushort4 r;
                r.x = f2h(acc[ct][lt][0]); r.y = f2h(acc[ct][lt][1]);
                r.z = f2h(acc[ct][lt][2]); r.w = f2h(acc[ct][lt][3]);
                *(ushort4*)&dst[(size_t)l * CQ_DIM + co_w + ct * 16 + quad * 4] = r;
            }
    } else {
        unsigned short* dst = vB + ((size_t)b * C_DIM + (co0 - 128)) * L_DIM;
#pragma unroll
        for (int ct = 0; ct < 2; ct++)
#pragma unroll
            for (int lt = 0; lt < 4; lt++) {
                const int l = l0 + l_w + lt * 16 + ln15;
#pragma unroll
                for (int r = 0; r < 4; r++) {
                    const int co = co_w + ct * 16 + quad * 4 + r;
                    dst[(size_t)co * L_DIM + l] = f2h(acc[ct][lt][r]);
                }
            }
    }
}

// ---------------------------------------------------------------------------
// Softmax stats via MFMA (fp16): m_j = max_i s[i,j], d_j = sum_i exp(s-m_j).
// ---------------------------------------------------------------------------
__global__ __launch_bounds__(256) void stats_k(const unsigned short* __restrict__ qT,
                                               const unsigned short* __restrict__ kT,
                                               float* __restrict__ mG,
                                               float* __restrict__ dG) {
    const int j0 = blockIdx.x * 64;
    const int b  = blockIdx.y;

    __shared__ unsigned short kTs[64 * 72];
    __shared__ unsigned short qTs[64 * 72];
    __shared__ float ss[64 * 68];
    __shared__ float red[4 * 64];
    __shared__ float m_s[64], d_s[64];

    const int tid = threadIdx.x;
    const int lane = tid & 63, w = tid >> 6;
    const int ln15 = lane & 15, quad = lane >> 4;
    const int jcol = tid & 63, part = tid >> 6;

    const unsigned short* qb = qT + (size_t)b * L_DIM * CQ_DIM;
    const unsigned short* kb = kT + (size_t)b * L_DIM * CQ_DIM;

    for (int idx = tid; idx < 64 * 8; idx += 256) {
        int r = idx >> 3, c8 = idx & 7;
        *(float4*)&kTs[r * 72 + c8 * 8] = *(const float4*)&kb[(size_t)(j0 + r) * CQ_DIM + c8 * 8];
    }
    if (tid < 64) { m_s[tid] = -1e30f; d_s[tid] = 0.f; }

    for (int i0 = 0; i0 < L_DIM; i0 += 64) {
        __syncthreads();
        for (int idx = tid; idx < 64 * 8; idx += 256) {
            int r = idx >> 3, c8 = idx & 7;
            *(float4*)&qTs[r * 72 + c8 * 8] = *(const float4*)&qb[(size_t)(i0 + r) * CQ_DIM + c8 * 8];
        }
        __syncthreads();

        f32x4 acc[4] = {};
#pragma unroll
        for (int cc = 0; cc < 2; cc++) {
            const f16x8 bfr = *(const f16x8*)&kTs[(w * 16 + ln15) * 72 + cc * 32 + quad * 8];
#pragma unroll
            for (int it = 0; it < 4; it++) {
                const f16x8 afr = *(const f16x8*)&qTs[(it * 16 + ln15) * 72 + cc * 32 + quad * 8];
                acc[it] = __builtin_amdgcn_mfma_f32_16x16x32_f16(afr, bfr, acc[it], 0, 0, 0);
            }
        }
#pragma unroll
        for (int it = 0; it < 4; it++)
#pragma unroll
            for (int r = 0; r < 4; r++)
                ss[(it * 16 + quad * 4 + r) * 68 + w * 16 + ln15] = acc[it][r];
        __syncthreads();

        float lm = -1e30f;
        for (int r = 0; r < 16; r++) lm = fmaxf(lm, ss[(part * 16 + r) * 68 + jcol]);
        red[part * 64 + jcol] = lm;
        __syncthreads();
        if (part == 0) {
            float mb = fmaxf(fmaxf(red[jcol], red[64 + jcol]),
                             fmaxf(red[128 + jcol], red[192 + jcol]));
            float mo = m_s[jcol];
            float mn = fmaxf(mo, mb);
            d_s[jcol] *= __expf(mo - mn);
            m_s[jcol] = mn;
        }
        __syncthreads();
        const float mj = m_s[jcol];
        float lsum = 0.f;
        for (int r = 0; r < 16; r++) lsum += __expf(ss[(part * 16 + r) * 68 + jcol] - mj);
        red[part * 64 + jcol] = lsum;
        __syncthreads();
        if (part == 0)
            d_s[jcol] += red[jcol] + red[64 + jcol] + red[128 + jcol] + red[192 + jcol];
    }
    __syncthreads();
    if (tid < 64) {
        mG[b * L_DIM + j0 + tid] = m_s[tid];
        dG[b * L_DIM + j0 + tid] = d_s[tid];
    }
}

// ---------------------------------------------------------------------------
// PV via MFMA (fp16): out[b,co,j] = gamma * sum_i v[b,co,i] * exp(s[i,j]-m_j)/d_j
// ---------------------------------------------------------------------------
__global__ __launch_bounds__(256) void pv_k(const unsigned short* __restrict__ qT,
                                            const unsigned short* __restrict__ kT,
                                            const unsigned short* __restrict__ vB,
                                            const float* __restrict__ mG,
                                            const float* __restrict__ dG,
                                            const float* __restrict__ gamma,
                                            float* __restrict__ out) {
    const int j0  = blockIdx.x * 128;
    const int co0 = blockIdx.y * 128;
    const int b   = blockIdx.z;

    __shared__ unsigned short kTs[128 * 72];
    __shared__ unsigned short qTs[64 * 72];
    __shared__ unsigned short vvs[128 * 72];
    __shared__ unsigned short pps[128 * 72];
    __shared__ float mj_s[128], id_s[128];

    const int tid = threadIdx.x;
    const int lane = tid & 63, w = tid >> 6;
    const int ln15 = lane & 15, quad = lane >> 4;

    const unsigned short* qb = qT + (size_t)b * L_DIM * CQ_DIM;
    const unsigned short* kb = kT + (size_t)b * L_DIM * CQ_DIM;
    const unsigned short* vb = vB + (size_t)b * C_DIM * L_DIM;

    for (int idx = tid; idx < 128 * 8; idx += 256) {
        int r = idx >> 3, c8 = idx & 7;
        *(float4*)&kTs[r * 72 + c8 * 8] = *(const float4*)&kb[(size_t)(j0 + r) * CQ_DIM + c8 * 8];
    }
    if (tid < 128) {
        mj_s[tid] = mG[b * L_DIM + j0 + tid];
        id_s[tid] = 1.0f / dG[b * L_DIM + j0 + tid];
    }

    const int wco = (w >> 1) * 64;
    const int wj  = (w & 1) * 64;
    const int sj  = w * 32;

    f32x4 oacc[4][4] = {};

    for (int i0 = 0; i0 < L_DIM; i0 += 64) {
        __syncthreads();
        for (int idx = tid; idx < 64 * 8; idx += 256) {
            int r = idx >> 3, c8 = idx & 7;
            *(float4*)&qTs[r * 72 + c8 * 8] = *(const float4*)&qb[(size_t)(i0 + r) * CQ_DIM + c8 * 8];
        }
        for (int idx = tid; idx < 128 * 8; idx += 256) {
            int r = idx >> 3, c8 = idx & 7;
            *(float4*)&vvs[r * 72 + c8 * 8] = *(const float4*)&vb[(size_t)(co0 + r) * L_DIM + i0 + c8 * 8];
        }
        __syncthreads();

        f32x4 sacc[4][2] = {};
#pragma unroll
        for (int cc = 0; cc < 2; cc++) {
            f16x8 bfr0 = *(const f16x8*)&kTs[(sj + ln15) * 72 + cc * 32 + quad * 8];
            f16x8 bfr1 = *(const f16x8*)&kTs[(sj + 16 + ln15) * 72 + cc * 32 + quad * 8];
#pragma unroll
            for (int it = 0; it < 4; it++) {
                const f16x8 afr = *(const f16x8*)&qTs[(it * 16 + ln15) * 72 + cc * 32 + quad * 8];
                sacc[it][0] = __builtin_amdgcn_mfma_f32_16x16x32_f16(afr, bfr0, sacc[it][0], 0, 0, 0);
                sacc[it][1] = __builtin_amdgcn_mfma_f32_16x16x32_f16(afr, bfr1, sacc[it][1], 0, 0, 0);
            }
        }
#pragma unroll
        for (int jt = 0; jt < 2; jt++) {
            const int j = sj + jt * 16 + ln15;
            const float m = mj_s[j], idv = id_s[j];
#pragma unroll
            for (int it = 0; it < 4; it++) {
                ushort4 r4;
                r4.x = f2h(__expf(sacc[it][jt][0] - m) * idv);
                r4.y = f2h(__expf(sacc[it][jt][1] - m) * idv);
                r4.z = f2h(__expf(sacc[it][jt][2] - m) * idv);
                r4.w = f2h(__expf(sacc[it][jt][3] - m) * idv);
                *(ushort4*)&pps[j * 72 + it * 16 + quad * 4] = r4;
            }
        }
        __syncthreads();

#pragma unroll
        for (int cc = 0; cc < 2; cc++) {
            f16x8 afr[4], bfr[4];
#pragma unroll
            for (int t = 0; t < 4; t++)
                afr[t] = *(const f16x8*)&vvs[(wco + t * 16 + ln15) * 72 + cc * 32 + quad * 8];
#pragma unroll
            for (int t = 0; t < 4; t++)
                bfr[t] = *(const f16x8*)&pps[(wj + t * 16 + ln15) * 72 + cc * 32 + quad * 8];
#pragma unroll
            for (int a = 0; a < 4; a++)
#pragma unroll
                for (int bb = 0; bb < 4; bb++)
                    oacc[a][bb] = __builtin_amdgcn_mfma_f32_16x16x32_f16(afr[a], bfr[bb], oacc[a][bb], 0, 0, 0);
        }
    }

    const float g = gamma[0];
#pragma unroll
    for (int a = 0; a < 4; a++)
#pragma unroll
        for (int r = 0; r < 4; r++) {
            const int co = co0 + wco + a * 16 + quad * 4 + r;
            float* ob = out + ((size_t)b * C_DIM + co) * L_DIM + j0 + wj;
#pragma unroll
            for (int bb = 0; bb < 4; bb++)
                ob[bb * 16 + ln15] = oacc[a][bb][r] * g;
        }
}

// ---------------------------------------------------------------------------
extern "C" void kernel_launch(void* const* d_in, const int* in_sizes, int n_in,
                              void* d_out, int out_size, void* d_ws, size_t ws_size,
                              hipStream_t stream) {
    const float* x     = (const float*)d_in[0];
    const float* Wq    = (const float*)d_in[1];
    const float* Wk    = (const float*)d_in[2];
    const float* Wv    = (const float*)d_in[3];
    const float* gamma = (const float*)d_in[4];
    float* out = (float*)d_out;

    unsigned short* ws_h = (unsigned short*)d_ws;
    unsigned short* qT = ws_h;                        // 8*2048*64   = 1,048,576
    unsigned short* kT = qT + 1048576;
    unsigned short* vB = kT + 1048576;                // 8*512*2048  = 8,388,608
    unsigned short* xT = vB + 8388608;                // 8*2048*512  = 8,388,608
    unsigned short* Wh = xT + 8388608;                // 3*640*512   = 983,040
    float* mG = (float*)(Wh + 983040);                // 16,384 floats
    float* dG = mG + 16384;                           // total ~39.9 MB

    prep_w  <<<3840, 256, 0, stream>>>(Wq, Wk, Wv, Wh);
    prep_x  <<<dim3(32, 8, 8), 256, 0, stream>>>(x, xT);
    conv_all<<<dim3(16, 10, 8), 256, 0, stream>>>(Wh, xT, qT, kT, vB);
    stats_k <<<dim3(32, 8), 256, 0, stream>>>(qT, kT, mG, dG);
    pv_k    <<<dim3(16, 4, 8), 256, 0, stream>>>(qT, kT, vB, mG, dG, gamma, out);
}

// Round 5
// 282.012 us; speedup vs baseline: 6.4085x; 1.1096x over previous
//
#include <hip/hip_runtime.h>
#include <cstddef>

#define L_DIM 2048
#define C_DIM 512
#define CQ_DIM 64
#define B_DIM 8

typedef _Float16 f16x8 __attribute__((ext_vector_type(8)));
typedef float f32x4 __attribute__((ext_vector_type(4)));

__device__ __forceinline__ unsigned short f2h(float f) {
    union { _Float16 h; unsigned short u; } v;
    v.h = (_Float16)f;
    return v.u;
}

// ---------------------------------------------------------------------------
// prep_w: Wq/Wk/Wv (fp32 [co][ci][3]) -> Wh fp16 [t][640co][512ci]
// co 0..63 = q, 64..127 = k, 128..639 = v
// ---------------------------------------------------------------------------
__global__ __launch_bounds__(256) void prep_w(const float* __restrict__ Wq,
                                              const float* __restrict__ Wk,
                                              const float* __restrict__ Wv,
                                              unsigned short* __restrict__ Wh) {
    const int idx = blockIdx.x * 256 + threadIdx.x;   // < 3*640*512
    const int ci = idx & 511;
    const int co = (idx >> 9) % 640;
    const int t  = idx / (640 * 512);
    float w;
    if (co < 64)       w = Wq[(size_t)co * 1536 + ci * 3 + t];
    else if (co < 128) w = Wk[(size_t)(co - 64) * 1536 + ci * 3 + t];
    else               w = Wv[(size_t)(co - 128) * 1536 + ci * 3 + t];
    Wh[idx] = f2h(w);
}

// ---------------------------------------------------------------------------
// prep_x: x fp32 [b][ci][l] -> xT fp16 [b][l][512ci]. 64ci x 64l tile per block.
// ---------------------------------------------------------------------------
__global__ __launch_bounds__(256) void prep_x(const float* __restrict__ x,
                                              unsigned short* __restrict__ xT) {
    const int l0  = blockIdx.x * 64;
    const int ci0 = blockIdx.y * 64;
    const int b   = blockIdx.z;

    __shared__ float xs[64][68];
    const int tid = threadIdx.x;
    const float* xb = x + ((size_t)b * C_DIM + ci0) * L_DIM;

    for (int idx = tid; idx < 64 * 16; idx += 256) {
        int ci = idx >> 4, lq = idx & 15;
        *(float4*)&xs[ci][lq * 4] = *(const float4*)&xb[(size_t)ci * L_DIM + l0 + lq * 4];
    }
    __syncthreads();

    unsigned short* ob = xT + ((size_t)b * L_DIM + l0) * C_DIM + ci0;
    for (int idx = tid; idx < 64 * 8; idx += 256) {
        int l = idx >> 3, c8 = idx & 7;
        ushort4 r0, r1;
        r0.x = f2h(xs[c8 * 8 + 0][l]); r0.y = f2h(xs[c8 * 8 + 1][l]);
        r0.z = f2h(xs[c8 * 8 + 2][l]); r0.w = f2h(xs[c8 * 8 + 3][l]);
        r1.x = f2h(xs[c8 * 8 + 4][l]); r1.y = f2h(xs[c8 * 8 + 5][l]);
        r1.z = f2h(xs[c8 * 8 + 6][l]); r1.w = f2h(xs[c8 * 8 + 7][l]);
        *(ushort4*)&ob[(size_t)l * C_DIM + c8 * 8] = r0;
        *(ushort4*)&ob[(size_t)l * C_DIM + c8 * 8 + 4] = r1;
    }
}

// ---------------------------------------------------------------------------
// conv_all: out[co,l] = sum_t sum_ci Wh[t][co][ci] * x[ci][l+t-1] via MFMA.
// Block tile 64co x 128l, 4 waves each 32co x 64l. ci chunks of 32.
// co0 == 0 -> qT (transposed), co0 == 64 -> kT, else vB natural [co][l].
// ---------------------------------------------------------------------------
__global__ __launch_bounds__(256) void conv_all(const unsigned short* __restrict__ Wh,
                                                const unsigned short* __restrict__ xT,
                                                unsigned short* __restrict__ qT,
                                                unsigned short* __restrict__ kT,
                                                unsigned short* __restrict__ vB) {
    const int l0  = blockIdx.x * 128;
    const int co0 = blockIdx.y * 64;
    const int b   = blockIdx.z;

    __shared__ unsigned short As[3][64][40];   // [t][co][ci32] rows padded to 40
    __shared__ unsigned short Bs[130][40];     // [la][ci32], la 0 == l0-1

    const int tid  = threadIdx.x;
    const int lane = tid & 63, w = tid >> 6;
    const int ln15 = lane & 15, quad = lane >> 4;

    const int co_w = (w & 1) * 32;   // wave's co offset within 64
    const int l_w  = (w >> 1) * 64;  // wave's l offset within 128

    const unsigned short* xb = xT + (size_t)b * L_DIM * C_DIM;

    f32x4 acc[2][4] = {};   // [ct co-tile][lt l-tile]

    for (int ci0 = 0; ci0 < C_DIM; ci0 += 32) {
        __syncthreads();
        // stage A: 3t x 64co x 32ci (float4 = 8 shorts)
        for (int idx = tid; idx < 768; idx += 256) {
            int t = idx >> 8, co = (idx >> 2) & 63, c8 = idx & 3;
            *(float4*)&As[t][co][c8 * 8] =
                *(const float4*)&Wh[(((size_t)t * 640) + co0 + co) * C_DIM + ci0 + c8 * 8];
        }
        // stage B: 130 rows (l0-1 .. l0+128) x 32ci
        for (int idx = tid; idx < 520; idx += 256) {
            int la = idx >> 2, c8 = idx & 3;
            int l = l0 - 1 + la;
            float4 vx = {0.f, 0.f, 0.f, 0.f};
            if (l >= 0 && l < L_DIM)
                vx = *(const float4*)&xb[(size_t)l * C_DIM + ci0 + c8 * 8];
            *(float4*)&Bs[la][c8 * 8] = vx;
        }
        __syncthreads();

#pragma unroll
        for (int t = 0; t < 3; t++) {
            f16x8 a[2], bfr[4];
#pragma unroll
            for (int ct = 0; ct < 2; ct++)
                a[ct] = *(const f16x8*)&As[t][co_w + ct * 16 + ln15][quad * 8];
#pragma unroll
            for (int lt = 0; lt < 4; lt++)
                bfr[lt] = *(const f16x8*)&Bs[l_w + lt * 16 + ln15 + t][quad * 8];
#pragma unroll
            for (int ct = 0; ct < 2; ct++)
#pragma unroll
                for (int lt = 0; lt < 4; lt++)
                    acc[ct][lt] = __builtin_amdgcn_mfma_f32_16x16x32_f16(a[ct], bfr[lt], acc[ct][lt], 0, 0, 0);
        }
    }

    if (co0 < 128) {
        // q or k: write transposed [l][64co]
        unsigned short* dst = (co0 == 0 ? qT : kT) + (size_t)b * L_DIM * CQ_DIM;
#pragma unroll
        for (int ct = 0; ct < 2; ct++)
#pragma unroll
            for (int lt = 0; lt < 4; lt++) {
                const int l = l0 + l_w + lt * 16 + ln15;
                ushort4 r;
                r.x = f2h(acc[ct][lt][0]); r.y = f2h(acc[ct][lt][1]);
                r.z = f2h(acc[ct][lt][2]); r.w = f2h(acc[ct][lt][3]);
                *(ushort4*)&dst[(size_t)l * CQ_DIM + co_w + ct * 16 + quad * 4] = r;
            }
    } else {
        unsigned short* dst = vB + ((size_t)b * C_DIM + (co0 - 128)) * L_DIM;
#pragma unroll
        for (int ct = 0; ct < 2; ct++)
#pragma unroll
            for (int lt = 0; lt < 4; lt++) {
                const int l = l0 + l_w + lt * 16 + ln15;
#pragma unroll
                for (int r = 0; r < 4; r++) {
                    const int co = co_w + ct * 16 + quad * 4 + r;
                    dst[(size_t)co * L_DIM + l] = f2h(acc[ct][lt][r]);
                }
            }
    }
}

// ---------------------------------------------------------------------------
// Fused attention with ONLINE softmax (over i axis):
// out[b,co,j] = gamma/l_j * sum_i v[b,co,i] * exp(s[i,j]-m_j)
// m,l maintained online per j in registers of the scores-phase wave that owns j
// (redundant across its 64 lanes via shfl_xor reductions). PV accumulators are
// rescaled by alpha[j]=exp(m_old-m_new) each K-iter (alpha passed via LDS).
// Block: 256 threads (4 waves), out tile 128co x 128j. Grid (16 j, 4 co, 8 b).
// ---------------------------------------------------------------------------
__global__ __launch_bounds__(256) void pv_k(const unsigned short* __restrict__ qT,
                                            const unsigned short* __restrict__ kT,
                                            const unsigned short* __restrict__ vB,
                                            const float* __restrict__ gamma,
                                            float* __restrict__ out) {
    const int j0  = blockIdx.x * 128;
    const int co0 = blockIdx.y * 128;
    const int b   = blockIdx.z;

    __shared__ unsigned short kTs[128 * 72];  // [j][c]
    __shared__ unsigned short qTs[64 * 72];   // [i][c]
    __shared__ unsigned short vvs[128 * 72];  // [co][i]
    __shared__ unsigned short pps[128 * 72];  // [j][i] (unnormalized p, fp16)
    __shared__ float al_s[128];               // per-iter alpha[j]; reused for l at end

    const int tid = threadIdx.x;
    const int lane = tid & 63, w = tid >> 6;
    const int ln15 = lane & 15, quad = lane >> 4;

    const unsigned short* qb = qT + (size_t)b * L_DIM * CQ_DIM;
    const unsigned short* kb = kT + (size_t)b * L_DIM * CQ_DIM;
    const unsigned short* vb = vB + (size_t)b * C_DIM * L_DIM;

    for (int idx = tid; idx < 128 * 8; idx += 256) {
        int r = idx >> 3, c8 = idx & 7;
        *(float4*)&kTs[r * 72 + c8 * 8] = *(const float4*)&kb[(size_t)(j0 + r) * CQ_DIM + c8 * 8];
    }

    const int wco = (w >> 1) * 64;  // PV phase: wave's co range within 128
    const int wj  = (w & 1) * 64;   // PV phase: wave's j range within 128
    const int sj  = w * 32;         // scores phase: wave's j range within 128

    f32x4 oacc[4][4] = {};
    float m_run[2] = {-1e30f, -1e30f};   // online max for j = sj + jt*16 + ln15
    float l_run[2] = {0.f, 0.f};         // online denom (redundant across lanes)

    for (int i0 = 0; i0 < L_DIM; i0 += 64) {
        __syncthreads();
        for (int idx = tid; idx < 64 * 8; idx += 256) {
            int r = idx >> 3, c8 = idx & 7;
            *(float4*)&qTs[r * 72 + c8 * 8] = *(const float4*)&qb[(size_t)(i0 + r) * CQ_DIM + c8 * 8];
        }
        for (int idx = tid; idx < 128 * 8; idx += 256) {
            int r = idx >> 3, c8 = idx & 7;
            *(float4*)&vvs[r * 72 + c8 * 8] = *(const float4*)&vb[(size_t)(co0 + r) * L_DIM + i0 + c8 * 8];
        }
        __syncthreads();

        // scores: wave computes S[64i x 32j] at j = sj..sj+32
        f32x4 sacc[4][2] = {};
#pragma unroll
        for (int cc = 0; cc < 2; cc++) {
            f16x8 bfr0 = *(const f16x8*)&kTs[(sj + ln15) * 72 + cc * 32 + quad * 8];
            f16x8 bfr1 = *(const f16x8*)&kTs[(sj + 16 + ln15) * 72 + cc * 32 + quad * 8];
#pragma unroll
            for (int it = 0; it < 4; it++) {
                const f16x8 afr = *(const f16x8*)&qTs[(it * 16 + ln15) * 72 + cc * 32 + quad * 8];
                sacc[it][0] = __builtin_amdgcn_mfma_f32_16x16x32_f16(afr, bfr0, sacc[it][0], 0, 0, 0);
                sacc[it][1] = __builtin_amdgcn_mfma_f32_16x16x32_f16(afr, bfr1, sacc[it][1], 0, 0, 0);
            }
        }

        // online softmax update + p = exp(s - m_new) -> fp16 -> pps[j][i]
#pragma unroll
        for (int jt = 0; jt < 2; jt++) {
            const int j = sj + jt * 16 + ln15;
            // block max over this lane's 16 i-values, then across quads
            float bm = -1e30f;
#pragma unroll
            for (int it = 0; it < 4; it++)
#pragma unroll
                for (int r = 0; r < 4; r++)
                    bm = fmaxf(bm, sacc[it][jt][r]);
            bm = fmaxf(bm, __shfl_xor(bm, 16, 64));
            bm = fmaxf(bm, __shfl_xor(bm, 32, 64));
            const float m_new = fmaxf(m_run[jt], bm);
            const float alpha = __expf(m_run[jt] - m_new);
            m_run[jt] = m_new;

            float lsum = 0.f;
#pragma unroll
            for (int it = 0; it < 4; it++) {
                float p0 = __expf(sacc[it][jt][0] - m_new);
                float p1 = __expf(sacc[it][jt][1] - m_new);
                float p2 = __expf(sacc[it][jt][2] - m_new);
                float p3 = __expf(sacc[it][jt][3] - m_new);
                lsum += (p0 + p1) + (p2 + p3);
                ushort4 r4;
                r4.x = f2h(p0); r4.y = f2h(p1); r4.z = f2h(p2); r4.w = f2h(p3);
                *(ushort4*)&pps[j * 72 + it * 16 + quad * 4] = r4;
            }
            lsum += __shfl_xor(lsum, 16, 64);
            lsum += __shfl_xor(lsum, 32, 64);
            l_run[jt] = l_run[jt] * alpha + lsum;
            if (quad == 0) al_s[j] = alpha;
        }
        __syncthreads();

        // PV: rescale O by alpha[j], then oacc += V[64co x 64i] * P[64i x 64j]
#pragma unroll
        for (int bb = 0; bb < 4; bb++) {
            const float a_bb = al_s[wj + bb * 16 + ln15];
#pragma unroll
            for (int a = 0; a < 4; a++)
#pragma unroll
                for (int r = 0; r < 4; r++)
                    oacc[a][bb][r] *= a_bb;
        }
#pragma unroll
        for (int cc = 0; cc < 2; cc++) {
            f16x8 afr[4], bfr[4];
#pragma unroll
            for (int t = 0; t < 4; t++)
                afr[t] = *(const f16x8*)&vvs[(wco + t * 16 + ln15) * 72 + cc * 32 + quad * 8];
#pragma unroll
            for (int t = 0; t < 4; t++)
                bfr[t] = *(const f16x8*)&pps[(wj + t * 16 + ln15) * 72 + cc * 32 + quad * 8];
#pragma unroll
            for (int a = 0; a < 4; a++)
#pragma unroll
                for (int bb = 0; bb < 4; bb++)
                    oacc[a][bb] = __builtin_amdgcn_mfma_f32_16x16x32_f16(afr[a], bfr[bb], oacc[a][bb], 0, 0, 0);
        }
    }

    // publish l (reuse al_s), then normalized epilogue
    __syncthreads();
    if (quad == 0) {
        al_s[sj + ln15] = l_run[0];
        al_s[sj + 16 + ln15] = l_run[1];
    }
    __syncthreads();

    const float g = gamma[0];
    float inv[4];
#pragma unroll
    for (int bb = 0; bb < 4; bb++)
        inv[bb] = g / al_s[wj + bb * 16 + ln15];

#pragma unroll
    for (int a = 0; a < 4; a++)
#pragma unroll
        for (int r = 0; r < 4; r++) {
            const int co = co0 + wco + a * 16 + quad * 4 + r;
            float* ob = out + ((size_t)b * C_DIM + co) * L_DIM + j0 + wj;
#pragma unroll
            for (int bb = 0; bb < 4; bb++)
                ob[bb * 16 + ln15] = oacc[a][bb][r] * inv[bb];
        }
}

// ---------------------------------------------------------------------------
extern "C" void kernel_launch(void* const* d_in, const int* in_sizes, int n_in,
                              void* d_out, int out_size, void* d_ws, size_t ws_size,
                              hipStream_t stream) {
    const float* x     = (const float*)d_in[0];
    const float* Wq    = (const float*)d_in[1];
    const float* Wk    = (const float*)d_in[2];
    const float* Wv    = (const float*)d_in[3];
    const float* gamma = (const float*)d_in[4];
    float* out = (float*)d_out;

    unsigned short* ws_h = (unsigned short*)d_ws;
    unsigned short* qT = ws_h;                        // 8*2048*64   = 1,048,576
    unsigned short* kT = qT + 1048576;
    unsigned short* vB = kT + 1048576;                // 8*512*2048  = 8,388,608
    unsigned short* xT = vB + 8388608;                // 8*2048*512  = 8,388,608
    unsigned short* Wh = xT + 8388608;                // 3*640*512   = 983,040
    // total ~39.7 MB

    prep_w  <<<3840, 256, 0, stream>>>(Wq, Wk, Wv, Wh);
    prep_x  <<<dim3(32, 8, 8), 256, 0, stream>>>(x, xT);
    conv_all<<<dim3(16, 10, 8), 256, 0, stream>>>(Wh, xT, qT, kT, vB);
    pv_k    <<<dim3(16, 4, 8), 256, 0, stream>>>(qT, kT, vB, gamma, out);
}